// Round 3
// baseline (367.576 us; speedup 1.0000x reference)
//
#include <hip/hip_runtime.h>
#include <cstdint>
#include <cstddef>

#define N_NODES 100000
#define E_EDGES 1600000
#define HCH 128
#define NHEADS 8
#define HDIM 16

typedef unsigned int uint;
typedef unsigned short ushort;
typedef __attribute__((ext_vector_type(8))) short short8;
typedef __attribute__((ext_vector_type(4))) float floatx4;
typedef __attribute__((ext_vector_type(2))) float floatx2;

__device__ __forceinline__ ushort f2bf(float f) {
    uint u = __float_as_uint(f);
    u = (u + 0x7fff + ((u >> 16) & 1)) >> 16;
    return (ushort)u;
}
__device__ __forceinline__ float bflo(uint p) { return __uint_as_float(p << 16); }
__device__ __forceinline__ float bfhi(uint p) { return __uint_as_float(p & 0xffff0000u); }

// ================= MFMA GEMMs =================
#define LDSPAD 8
#define SMEM_BYTES (17408 + 34816)

// Fused qkv: one pass over A, loop 3 weight matrices.
// qe row = 128B plain channel order (fp8).
// kv row = 256B: per head (32B): [k0-3][k4-7][v0-3][v4-7][k8-11][k12-15][v8-11][v12-15].
__global__ __launch_bounds__(256) void gemm_qkv(
    const float* __restrict__ A,
    const float* __restrict__ Wq, const float* __restrict__ Wk, const float* __restrict__ Wv,
    const float* __restrict__ bq, const float* __restrict__ bk, const float* __restrict__ bv,
    unsigned char* __restrict__ qe, unsigned char* __restrict__ kvb,
    int M)
{
    __shared__ __align__(16) char smem[SMEM_BYTES];
    ushort (*As)[HCH + LDSPAD] = (ushort(*)[HCH + LDSPAD])smem;
    ushort (*Wt)[HCH + LDSPAD] = (ushort(*)[HCH + LDSPAD])(smem + 17408);
    float (*Cs)[132] = (float(*)[132])(smem + 17408);

    const int t = threadIdx.x;
    const int mb = blockIdx.x * 64;

    // stage A tile once (fp32 -> bf16)
#pragma unroll
    for (int i = 0; i < 8; i++) {
        int p = t + i * 256;
        int row = p >> 5, c4 = p & 31;       // 32 float4 = 128 fp32 channels
        int g = mb + row;
        float4 a4 = make_float4(0.f, 0.f, 0.f, 0.f);
        if (g < M) a4 = *(const float4*)(A + (size_t)g * HCH + c4 * 4);
        uint lo = (uint)f2bf(a4.x) | ((uint)f2bf(a4.y) << 16);
        uint hi = (uint)f2bf(a4.z) | ((uint)f2bf(a4.w) << 16);
        *(uint2*)(&As[row][c4 * 4]) = make_uint2(lo, hi);
    }

    const int lane = t & 63;
    const int w = t >> 6;
    const int m_l = lane & 15;
    const int q_l = lane >> 4;

    for (int mode = 0; mode < 3; mode++) {
        const float* W    = (mode == 0) ? Wq : (mode == 1) ? Wk : Wv;
        const float* bias = (mode == 0) ? bq : (mode == 1) ? bk : bv;

#pragma unroll
        for (int i = 0; i < 16; i++) {
            int p = t + i * 256;
            int n = p & 127, k4 = p >> 7;
            float w0 = W[(size_t)(k4 * 4 + 0) * HCH + n];
            float w1 = W[(size_t)(k4 * 4 + 1) * HCH + n];
            float w2 = W[(size_t)(k4 * 4 + 2) * HCH + n];
            float w3 = W[(size_t)(k4 * 4 + 3) * HCH + n];
            uint lo = (uint)f2bf(w0) | ((uint)f2bf(w1) << 16);
            uint hi = (uint)f2bf(w2) | ((uint)f2bf(w3) << 16);
            *(uint2*)(&Wt[n][k4 * 4]) = make_uint2(lo, hi);
        }
        __syncthreads();

        floatx4 acc[8];
#pragma unroll
        for (int tl = 0; tl < 8; tl++) acc[tl] = (floatx4){0.f, 0.f, 0.f, 0.f};

#pragma unroll
        for (int ks = 0; ks < HCH; ks += 32) {
            short8 af = *(const short8*)(&As[w * 16 + m_l][ks + q_l * 8]);
#pragma unroll
            for (int tl = 0; tl < 8; tl++) {
                short8 bf = *(const short8*)(&Wt[tl * 16 + m_l][ks + q_l * 8]);
                acc[tl] = __builtin_amdgcn_mfma_f32_16x16x32_bf16(af, bf, acc[tl], 0, 0, 0);
            }
        }
        __syncthreads();

#pragma unroll
        for (int tl = 0; tl < 8; tl++)
#pragma unroll
            for (int r = 0; r < 4; r++)
                Cs[w * 16 + q_l * 4 + r][tl * 16 + m_l] = acc[tl][r];
        __syncthreads();

#pragma unroll
        for (int i = 0; i < 8; i++) {
            int p = t + i * 256;
            int row = p >> 5, c4 = p & 31;
            int g = mb + row;
            if (g >= M) continue;
            float4 b4 = *(const float4*)(bias + c4 * 4);
            float v0 = Cs[row][c4 * 4 + 0] + b4.x;
            float v1 = Cs[row][c4 * 4 + 1] + b4.y;
            float v2 = Cs[row][c4 * 4 + 2] + b4.z;
            float v3 = Cs[row][c4 * 4 + 3] + b4.w;
            int r = __builtin_amdgcn_cvt_pk_fp8_f32(v0, v1, 0, false);
            r = __builtin_amdgcn_cvt_pk_fp8_f32(v2, v3, r, true);
            if (mode == 0) {
                *(int*)(qe + (size_t)g * 128 + c4 * 4) = r;
            } else {
                size_t boff = (size_t)g * 256 + (c4 >> 2) * 32 + ((c4 >> 1) & 1) * 16
                     + (c4 & 1) * 4 + (mode == 2 ? 8 : 0);
                *(int*)(kvb + boff) = r;
            }
        }
        __syncthreads();
    }
}

// out = x + (attended_bf16_unnorm * invL[head]) @ Wo + bo
__global__ __launch_bounds__(256) void gemm_out(
    const ushort* __restrict__ A, const float* __restrict__ W,
    const float* __restrict__ bias, const float* __restrict__ res,
    const float* __restrict__ head_invl,
    float* __restrict__ C, int M)
{
    __shared__ __align__(16) char smem[SMEM_BYTES];
    ushort (*As)[HCH + LDSPAD] = (ushort(*)[HCH + LDSPAD])smem;
    ushort (*Wt)[HCH + LDSPAD] = (ushort(*)[HCH + LDSPAD])(smem + 17408);
    float (*Cs)[132] = (float(*)[132])(smem + 17408);

    const int t = threadIdx.x;
    const int mb = blockIdx.x * 64;

    __shared__ float invl_s[8];
    if (t < 8) invl_s[t] = head_invl[t];
    __syncthreads();

#pragma unroll
    for (int i = 0; i < 8; i++) {
        int p = t + i * 256;
        int row = p >> 5, cu2 = p & 31;     // 32 uint2 per row = 128 channels
        int g = mb + row;
        uint2 a = make_uint2(0, 0);
        if (g < M) a = *(const uint2*)(A + (size_t)g * HCH + cu2 * 4);
        float invl = invl_s[cu2 >> 2];      // 4 channels per uint2, 16 per head
        float f0 = bflo(a.x) * invl, f1 = bfhi(a.x) * invl;
        float f2 = bflo(a.y) * invl, f3 = bfhi(a.y) * invl;
        uint lo = (uint)f2bf(f0) | ((uint)f2bf(f1) << 16);
        uint hi = (uint)f2bf(f2) | ((uint)f2bf(f3) << 16);
        *(uint2*)(&As[row][cu2 * 4]) = make_uint2(lo, hi);
    }
#pragma unroll
    for (int i = 0; i < 16; i++) {
        int p = t + i * 256;
        int n = p & 127, k4 = p >> 7;
        float w0 = W[(size_t)(k4 * 4 + 0) * HCH + n];
        float w1 = W[(size_t)(k4 * 4 + 1) * HCH + n];
        float w2 = W[(size_t)(k4 * 4 + 2) * HCH + n];
        float w3 = W[(size_t)(k4 * 4 + 3) * HCH + n];
        uint lo = (uint)f2bf(w0) | ((uint)f2bf(w1) << 16);
        uint hi = (uint)f2bf(w2) | ((uint)f2bf(w3) << 16);
        *(uint2*)(&Wt[n][k4 * 4]) = make_uint2(lo, hi);
    }
    __syncthreads();

    const int lane = t & 63;
    const int w = t >> 6;
    const int m_l = lane & 15;
    const int q_l = lane >> 4;

    floatx4 acc[8];
#pragma unroll
    for (int tl = 0; tl < 8; tl++) acc[tl] = (floatx4){0.f, 0.f, 0.f, 0.f};

#pragma unroll
    for (int ks = 0; ks < HCH; ks += 32) {
        short8 af = *(const short8*)(&As[w * 16 + m_l][ks + q_l * 8]);
#pragma unroll
        for (int tl = 0; tl < 8; tl++) {
            short8 bf = *(const short8*)(&Wt[tl * 16 + m_l][ks + q_l * 8]);
            acc[tl] = __builtin_amdgcn_mfma_f32_16x16x32_bf16(af, bf, acc[tl], 0, 0, 0);
        }
    }
    __syncthreads();

#pragma unroll
    for (int tl = 0; tl < 8; tl++)
#pragma unroll
        for (int r = 0; r < 4; r++)
            Cs[w * 16 + q_l * 4 + r][tl * 16 + m_l] = acc[tl][r];
    __syncthreads();

#pragma unroll
    for (int i = 0; i < 8; i++) {
        int p = t + i * 256;
        int row = p >> 5, c4 = p & 31;
        int g = mb + row;
        if (g >= M) continue;
        float4 b4 = *(const float4*)(bias + c4 * 4);
        float4 r4 = *(const float4*)(res + (size_t)g * HCH + c4 * 4);
        float4 o;
        o.x = Cs[row][c4 * 4 + 0] + b4.x + r4.x;
        o.y = Cs[row][c4 * 4 + 1] + b4.y + r4.y;
        o.z = Cs[row][c4 * 4 + 2] + b4.z + r4.z;
        o.w = Cs[row][c4 * 4 + 3] + b4.w + r4.w;
        *(float4*)(C + (size_t)g * HCH + c4 * 4) = o;
    }
}

// ================= two-pass bucketed counting sort by dst =================
constexpr int BSHIFT = 8;
constexpr int NBUCK  = ((N_NODES - 1) >> BSHIFT) + 1;   // 391
constexpr int S1_GRID = 256;
constexpr int S1_CH   = (E_EDGES + S1_GRID - 1) / S1_GRID;  // 6250
constexpr int S2_CAP  = 6144;

__global__ __launch_bounds__(256) void bucket_hist(
    const int* __restrict__ dst, int* __restrict__ bucket_total)
{
    __shared__ int cnt[NBUCK];
    const int t = threadIdx.x;
    for (int b = t; b < NBUCK; b += 256) cnt[b] = 0;
    __syncthreads();
    const int e0 = blockIdx.x * S1_CH;
    const int n = min(S1_CH, E_EDGES - e0);
    for (int i = t; i < n; i += 256)
        atomicAdd(&cnt[dst[e0 + i] >> BSHIFT], 1);
    __syncthreads();
    for (int b = t; b < NBUCK; b += 256)
        if (cnt[b]) atomicAdd(&bucket_total[b], cnt[b]);
}

__global__ __launch_bounds__(512) void bucket_scan(
    const int* __restrict__ bucket_total, int* __restrict__ bucket_start,
    int* __restrict__ bucket_cursor, int* __restrict__ offsets)
{
    __shared__ int s[512];
    const int t = threadIdx.x;
    int v = (t < NBUCK) ? bucket_total[t] : 0;
    s[t] = v;
    __syncthreads();
    for (int off = 1; off < 512; off <<= 1) {
        int a = (t >= off) ? s[t - off] : 0;
        __syncthreads();
        s[t] += a;
        __syncthreads();
    }
    int excl = s[t] - v;
    if (t < NBUCK) { bucket_start[t] = excl; bucket_cursor[t] = excl; }
    if (t == 0) { bucket_start[NBUCK] = E_EDGES; offsets[N_NODES] = E_EDGES; }
}

__global__ __launch_bounds__(256) void sort_scatter1(
    const int* __restrict__ src, const int* __restrict__ dst,
    int* __restrict__ bucket_cursor, int2* __restrict__ tmp)
{
    __shared__ int ls[S1_CH];
    __shared__ int ld[S1_CH];
    __shared__ int cnt[NBUCK];
    const int t = threadIdx.x;
    for (int b = t; b < NBUCK; b += 256) cnt[b] = 0;
    __syncthreads();
    const int e0 = blockIdx.x * S1_CH;
    const int n = min(S1_CH, E_EDGES - e0);
    for (int i = t; i < n; i += 256) {
        int d = dst[e0 + i];
        ls[i] = src[e0 + i];
        ld[i] = d;
        atomicAdd(&cnt[d >> BSHIFT], 1);
    }
    __syncthreads();
    for (int b = t; b < NBUCK; b += 256) {
        int c = cnt[b];
        cnt[b] = c ? atomicAdd(&bucket_cursor[b], c) : 0;
    }
    __syncthreads();
    for (int i = t; i < n; i += 256) {
        int d = ld[i];
        int pos = atomicAdd(&cnt[d >> BSHIFT], 1);
        tmp[pos] = make_int2(ls[i], d);
    }
}

__global__ __launch_bounds__(256) void sort_scatter2(
    const int2* __restrict__ tmp, const int* __restrict__ bucket_start,
    int* __restrict__ psrc, int* __restrict__ offsets)
{
    __shared__ int2 le[S2_CAP];
    __shared__ int cnt[256];
    __shared__ int s[256];
    __shared__ int cur[256];
    const int t = threadIdx.x;
    const int b = blockIdx.x;
    const int bstart = bucket_start[b];
    const int n = bucket_start[b + 1] - bstart;
    cnt[t] = 0;
    __syncthreads();
    for (int i = t; i < n; i += 256) {
        int2 e = tmp[bstart + i];
        if (i < S2_CAP) le[i] = e;
        atomicAdd(&cnt[e.y & 255], 1);
    }
    __syncthreads();
    int v = cnt[t];
    s[t] = v;
    __syncthreads();
    for (int off = 1; off < 256; off <<= 1) {
        int a = (t >= off) ? s[t - off] : 0;
        __syncthreads();
        s[t] += a;
        __syncthreads();
    }
    int excl = s[t] - v;
    int node = (b << BSHIFT) + t;
    if (node < N_NODES) offsets[node] = bstart + excl;
    cur[t] = excl;
    __syncthreads();
    for (int i = t; i < n; i += 256) {
        int2 e = (i < S2_CAP) ? le[i] : tmp[bstart + i];
        int pos = bstart + atomicAdd(&cur[e.y & 255], 1);
        psrc[pos] = e.x;
    }
}

// ============ FUSED: per-dst segment reduce, fp8 kv, in-flight w = exp(q.k/4) ============
// Wave: 4 groups x 16 lanes; group g handles edges start+g, +4, ... of node d.
// Lane sub: 16B of the 256B kv row = 8 k-fp8 (.xy) + 8 v-fp8 (.zw), channels sub*8..+7.
// Pair lanes (xor 1) hold the two halves of head sub>>1; shfl_xor(1) completes the dot.
// 4 edges in flight per group; packed f32x2 math (v_pk_fma_f32).
constexpr int FU_BLOCKS = 2048;

__device__ __forceinline__ void edge_body(
    uint4 e, floatx2 q0, floatx2 q1, floatx2 q2, floatx2 q3,
    float& lsum, floatx2& a01, floatx2& a23, floatx2& a45, floatx2& a67)
{
    floatx2 dp = q0 * __builtin_amdgcn_cvt_pk_f32_fp8((int)e.x, false);
    dp += q1 * __builtin_amdgcn_cvt_pk_f32_fp8((int)e.x, true);
    dp += q2 * __builtin_amdgcn_cvt_pk_f32_fp8((int)e.y, false);
    dp += q3 * __builtin_amdgcn_cvt_pk_f32_fp8((int)e.y, true);
    float p = dp.x + dp.y;
    p += __shfl_xor(p, 1);
    float wgt = __expf(p * 0.25f);
    lsum += wgt;                       // both pair lanes count; halved in reduction
    floatx2 wv = {wgt, wgt};
    a01 += wv * __builtin_amdgcn_cvt_pk_f32_fp8((int)e.z, false);
    a23 += wv * __builtin_amdgcn_cvt_pk_f32_fp8((int)e.z, true);
    a45 += wv * __builtin_amdgcn_cvt_pk_f32_fp8((int)e.w, false);
    a67 += wv * __builtin_amdgcn_cvt_pk_f32_fp8((int)e.w, true);
}

__global__ __launch_bounds__(256) void edge_fused(
    const unsigned char* __restrict__ qe, const unsigned char* __restrict__ kv,
    const int* __restrict__ psrc, const int* __restrict__ offsets,
    ushort* __restrict__ attended, float* __restrict__ block_l)
{
    const int t = threadIdx.x;
    const int w = t >> 6;          // wave in block
    const int lane = t & 63;
    const int g = lane >> 4;       // edge group 0..3
    const int sub = lane & 15;     // 16B chunk within kv row

    float lsum = 0.f;

    for (int d = blockIdx.x * 4 + w; d < N_NODES; d += FU_BLOCKS * 4) {
        const int start = offsets[d];
        const int end   = offsets[d + 1];

        uint2 qw = *(const uint2*)(qe + (size_t)d * 128 + sub * 8);
        floatx2 q0 = __builtin_amdgcn_cvt_pk_f32_fp8((int)qw.x, false);
        floatx2 q1 = __builtin_amdgcn_cvt_pk_f32_fp8((int)qw.x, true);
        floatx2 q2 = __builtin_amdgcn_cvt_pk_f32_fp8((int)qw.y, false);
        floatx2 q3 = __builtin_amdgcn_cvt_pk_f32_fp8((int)qw.y, true);

        floatx2 a01 = {0.f, 0.f}, a23 = {0.f, 0.f}, a45 = {0.f, 0.f}, a67 = {0.f, 0.f};

        int i = start + g;
        // four edges in flight per group
        for (; i + 12 < end; i += 16) {
            int s0 = psrc[i];
            int s1 = psrc[i + 4];
            int s2 = psrc[i + 8];
            int s3 = psrc[i + 12];
            uint4 e0 = *(const uint4*)(kv + (size_t)s0 * 256 + sub * 16);
            uint4 e1 = *(const uint4*)(kv + (size_t)s1 * 256 + sub * 16);
            uint4 e2 = *(const uint4*)(kv + (size_t)s2 * 256 + sub * 16);
            uint4 e3 = *(const uint4*)(kv + (size_t)s3 * 256 + sub * 16);
            edge_body(e0, q0, q1, q2, q3, lsum, a01, a23, a45, a67);
            edge_body(e1, q0, q1, q2, q3, lsum, a01, a23, a45, a67);
            edge_body(e2, q0, q1, q2, q3, lsum, a01, a23, a45, a67);
            edge_body(e3, q0, q1, q2, q3, lsum, a01, a23, a45, a67);
        }
        for (; i < end; i += 4) {
            int s0 = psrc[i];
            uint4 e0 = *(const uint4*)(kv + (size_t)s0 * 256 + sub * 16);
            edge_body(e0, q0, q1, q2, q3, lsum, a01, a23, a45, a67);
        }

        // combine the 4 edge groups
        float a0 = a01.x, a1 = a01.y, a2 = a23.x, a3 = a23.y;
        float a4 = a45.x, a5 = a45.y, a6 = a67.x, a7 = a67.y;
        a0 += __shfl_xor(a0, 16); a0 += __shfl_xor(a0, 32);
        a1 += __shfl_xor(a1, 16); a1 += __shfl_xor(a1, 32);
        a2 += __shfl_xor(a2, 16); a2 += __shfl_xor(a2, 32);
        a3 += __shfl_xor(a3, 16); a3 += __shfl_xor(a3, 32);
        a4 += __shfl_xor(a4, 16); a4 += __shfl_xor(a4, 32);
        a5 += __shfl_xor(a5, 16); a5 += __shfl_xor(a5, 32);
        a6 += __shfl_xor(a6, 16); a6 += __shfl_xor(a6, 32);
        a7 += __shfl_xor(a7, 16); a7 += __shfl_xor(a7, 32);

        if (g == 0) {
            uint4 o;
            o.x = (uint)f2bf(a0) | ((uint)f2bf(a1) << 16);
            o.y = (uint)f2bf(a2) | ((uint)f2bf(a3) << 16);
            o.z = (uint)f2bf(a4) | ((uint)f2bf(a5) << 16);
            o.w = (uint)f2bf(a6) | ((uint)f2bf(a7) << 16);
            *(uint4*)(attended + (size_t)d * HCH + sub * 8) = o;
        }
    }

    // block-level per-head L reduction; head = (t&15)>>1, pair lanes double-count -> x0.5
    __shared__ float sl[256];
    sl[t] = lsum;
    __syncthreads();
    if (t < 8) {
        float L = 0.f;
        for (int base = 0; base < 256; base += 16)
            L += sl[base + 2 * t] + sl[base + 2 * t + 1];
        block_l[blockIdx.x * 8 + t] = 0.5f * L;
    }
}

__global__ __launch_bounds__(256) void reduce_l(
    const float* __restrict__ block_l, float* __restrict__ head_invl, int nblk)
{
    const int t = threadIdx.x;
    float l = 0.f;
    for (int i = t; i < nblk * 8; i += 256) l += block_l[i];
    __shared__ float sl[256];
    sl[t] = l;
    __syncthreads();
    if (t < 8) {
        float L = 0.f;
        for (int i = t; i < 256; i += 8) L += sl[i];
        head_invl[t] = 1.0f / L;
    }
}

extern "C" void kernel_launch(void* const* d_in, const int* in_sizes, int n_in,
                              void* d_out, int out_size, void* d_ws, size_t ws_size,
                              hipStream_t stream)
{
    const float* x  = (const float*)d_in[0];
    const int* eidx = (const int*)d_in[1];
    const float* Wq = (const float*)d_in[2];
    const float* bq = (const float*)d_in[3];
    const float* Wk = (const float*)d_in[4];
    const float* bk = (const float*)d_in[5];
    const float* Wv = (const float*)d_in[6];
    const float* bv = (const float*)d_in[7];
    const float* Wo = (const float*)d_in[8];
    const float* bo = (const float*)d_in[9];
    float* out = (float*)d_out;

    char* ws = (char*)d_ws;
    constexpr size_t SZ_Q8  = (size_t)N_NODES * HCH;          // 12.8 MB fp8 q
    constexpr size_t SZ_KV8 = (size_t)N_NODES * HCH * 2;      // 25.6 MB fp8 kv interleaved
    constexpr size_t SZ_ATT = (size_t)N_NODES * HCH * 2;      // 25.6 MB bf16 attended
    constexpr size_t SZ_PS  = (size_t)E_EDGES * sizeof(int);  // 6.4 MB
    constexpr size_t SZ_TMP = (size_t)E_EDGES * sizeof(int2); // 12.8 MB
    size_t off = 0;
    unsigned char* qe  = (unsigned char*)(ws + off); off += SZ_Q8;
    unsigned char* kvb = (unsigned char*)(ws + off); off += SZ_KV8;
    ushort* attended = (ushort*)(ws + off); off += SZ_ATT;
    int*    psrc     = (int*)(ws + off);    off += SZ_PS;
    int2*   tmp      = (int2*)(ws + off);   off += SZ_TMP;
    int*    offsets  = (int*)(ws + off);    off += ((size_t)N_NODES + 1) * 4 + 8;
    int*    bucket_total  = (int*)(ws + off); off += (NBUCK + 1) * 4;
    int*    bucket_start  = (int*)(ws + off); off += (NBUCK + 1) * 4;
    int*    bucket_cursor = (int*)(ws + off); off += (NBUCK + 1) * 4;
    float*  block_l   = (float*)(ws + off); off += (size_t)FU_BLOCKS * 8 * sizeof(float);
    float*  head_invl = (float*)(ws + off); off += 32;
    const int* src = eidx;
    const int* dst = eidx + E_EDGES;

    dim3 blk(256);
    const int gblocks = (N_NODES + 63) / 64;

    gemm_qkv<<<gblocks, blk, 0, stream>>>(x, Wq, Wk, Wv, bq, bk, bv, qe, kvb, N_NODES);

    hipMemsetAsync(bucket_total, 0, (NBUCK + 1) * 4, stream);
    bucket_hist<<<S1_GRID, blk, 0, stream>>>(dst, bucket_total);
    bucket_scan<<<1, 512, 0, stream>>>(bucket_total, bucket_start, bucket_cursor, offsets);
    sort_scatter1<<<S1_GRID, blk, 0, stream>>>(src, dst, bucket_cursor, tmp);
    sort_scatter2<<<NBUCK, blk, 0, stream>>>(tmp, bucket_start, psrc, offsets);

    edge_fused<<<FU_BLOCKS, blk, 0, stream>>>(qe, kvb, psrc, offsets, attended, block_l);
    reduce_l<<<1, blk, 0, stream>>>(block_l, head_invl, FU_BLOCKS);

    gemm_out<<<gblocks, blk, 0, stream>>>(attended, Wo, bo, x, head_invl, out, N_NODES);
}

// Round 4
// 333.436 us; speedup vs baseline: 1.1024x; 1.1024x over previous
//
#include <hip/hip_runtime.h>
#include <cstdint>
#include <cstddef>

#define N_NODES 100000
#define E_EDGES 1600000
#define HCH 128
#define NHEADS 8
#define HDIM 16

typedef unsigned int uint;
typedef unsigned short ushort;
typedef __attribute__((ext_vector_type(8))) short short8;
typedef __attribute__((ext_vector_type(4))) float floatx4;
typedef __attribute__((ext_vector_type(2))) float floatx2;

__device__ __forceinline__ ushort f2bf(float f) {
    uint u = __float_as_uint(f);
    u = (u + 0x7fff + ((u >> 16) & 1)) >> 16;
    return (ushort)u;
}
__device__ __forceinline__ float bflo(uint p) { return __uint_as_float(p << 16); }
__device__ __forceinline__ float bfhi(uint p) { return __uint_as_float(p & 0xffff0000u); }

// ================= MFMA GEMMs =================
#define LDSPAD 8
#define SMEM_BYTES (17408 + 34816)

// qkv (round-2 form: 3 parallel sub-grids via blockIdx.y). fp8 outputs.
// qe row = 128B plain channel order.
// kv row = 256B: per head (32B): [k0-3][k4-7][v0-3][v4-7][k8-11][k12-15][v8-11][v12-15].
__global__ __launch_bounds__(256) void gemm_qkv(
    const float* __restrict__ A,
    const float* __restrict__ Wq, const float* __restrict__ Wk, const float* __restrict__ Wv,
    const float* __restrict__ bq, const float* __restrict__ bk, const float* __restrict__ bv,
    unsigned char* __restrict__ qe, unsigned char* __restrict__ kvb,
    int M)
{
    __shared__ __align__(16) char smem[SMEM_BYTES];
    ushort (*As)[HCH + LDSPAD] = (ushort(*)[HCH + LDSPAD])smem;
    ushort (*Wt)[HCH + LDSPAD] = (ushort(*)[HCH + LDSPAD])(smem + 17408);
    float (*Cs)[132] = (float(*)[132])(smem + 17408);

    const int t = threadIdx.x;
    const int mb = blockIdx.x * 64;
    const int mode = blockIdx.y;
    const float* W;
    const float* bias;
    if (mode == 0)      { W = Wq; bias = bq; }
    else if (mode == 1) { W = Wk; bias = bk; }
    else                { W = Wv; bias = bv; }

#pragma unroll
    for (int i = 0; i < 8; i++) {
        int p = t + i * 256;
        int row = p >> 5, c4 = p & 31;       // 32 float4 = 128 fp32 channels
        int g = mb + row;
        float4 a4 = make_float4(0.f, 0.f, 0.f, 0.f);
        if (g < M) a4 = *(const float4*)(A + (size_t)g * HCH + c4 * 4);
        uint lo = (uint)f2bf(a4.x) | ((uint)f2bf(a4.y) << 16);
        uint hi = (uint)f2bf(a4.z) | ((uint)f2bf(a4.w) << 16);
        *(uint2*)(&As[row][c4 * 4]) = make_uint2(lo, hi);
    }
#pragma unroll
    for (int i = 0; i < 16; i++) {
        int p = t + i * 256;
        int n = p & 127, k4 = p >> 7;
        float w0 = W[(size_t)(k4 * 4 + 0) * HCH + n];
        float w1 = W[(size_t)(k4 * 4 + 1) * HCH + n];
        float w2 = W[(size_t)(k4 * 4 + 2) * HCH + n];
        float w3 = W[(size_t)(k4 * 4 + 3) * HCH + n];
        uint lo = (uint)f2bf(w0) | ((uint)f2bf(w1) << 16);
        uint hi = (uint)f2bf(w2) | ((uint)f2bf(w3) << 16);
        *(uint2*)(&Wt[n][k4 * 4]) = make_uint2(lo, hi);
    }
    __syncthreads();

    const int lane = t & 63;
    const int w = t >> 6;
    const int m_l = lane & 15;
    const int q_l = lane >> 4;

    floatx4 acc[8];
#pragma unroll
    for (int tl = 0; tl < 8; tl++) acc[tl] = (floatx4){0.f, 0.f, 0.f, 0.f};

#pragma unroll
    for (int ks = 0; ks < HCH; ks += 32) {
        short8 af = *(const short8*)(&As[w * 16 + m_l][ks + q_l * 8]);
#pragma unroll
        for (int tl = 0; tl < 8; tl++) {
            short8 bf = *(const short8*)(&Wt[tl * 16 + m_l][ks + q_l * 8]);
            acc[tl] = __builtin_amdgcn_mfma_f32_16x16x32_bf16(af, bf, acc[tl], 0, 0, 0);
        }
    }
    __syncthreads();

#pragma unroll
    for (int tl = 0; tl < 8; tl++)
#pragma unroll
        for (int r = 0; r < 4; r++)
            Cs[w * 16 + q_l * 4 + r][tl * 16 + m_l] = acc[tl][r];
    __syncthreads();

#pragma unroll
    for (int i = 0; i < 8; i++) {
        int p = t + i * 256;
        int row = p >> 5, c4 = p & 31;
        int g = mb + row;
        if (g >= M) continue;
        float4 b4 = *(const float4*)(bias + c4 * 4);
        float v0 = Cs[row][c4 * 4 + 0] + b4.x;
        float v1 = Cs[row][c4 * 4 + 1] + b4.y;
        float v2 = Cs[row][c4 * 4 + 2] + b4.z;
        float v3 = Cs[row][c4 * 4 + 3] + b4.w;
        int r = __builtin_amdgcn_cvt_pk_fp8_f32(v0, v1, 0, false);
        r = __builtin_amdgcn_cvt_pk_fp8_f32(v2, v3, r, true);
        if (mode == 0) {
            *(int*)(qe + (size_t)g * 128 + c4 * 4) = r;
        } else {
            size_t boff = (size_t)g * 256 + (c4 >> 2) * 32 + ((c4 >> 1) & 1) * 16
                 + (c4 & 1) * 4 + (mode == 2 ? 8 : 0);
            *(int*)(kvb + boff) = r;
        }
    }
}

// out = x + (attended_bf16_unnorm * invL[head]) @ Wo + bo
__global__ __launch_bounds__(256) void gemm_out(
    const ushort* __restrict__ A, const float* __restrict__ W,
    const float* __restrict__ bias, const float* __restrict__ res,
    const float* __restrict__ head_invl,
    float* __restrict__ C, int M)
{
    __shared__ __align__(16) char smem[SMEM_BYTES];
    ushort (*As)[HCH + LDSPAD] = (ushort(*)[HCH + LDSPAD])smem;
    ushort (*Wt)[HCH + LDSPAD] = (ushort(*)[HCH + LDSPAD])(smem + 17408);
    float (*Cs)[132] = (float(*)[132])(smem + 17408);

    const int t = threadIdx.x;
    const int mb = blockIdx.x * 64;

    __shared__ float invl_s[8];
    if (t < 8) invl_s[t] = head_invl[t];
    __syncthreads();

#pragma unroll
    for (int i = 0; i < 8; i++) {
        int p = t + i * 256;
        int row = p >> 5, cu2 = p & 31;     // 32 uint2 per row = 128 channels
        int g = mb + row;
        uint2 a = make_uint2(0, 0);
        if (g < M) a = *(const uint2*)(A + (size_t)g * HCH + cu2 * 4);
        float invl = invl_s[cu2 >> 2];      // 4 channels per uint2, 16 per head
        float f0 = bflo(a.x) * invl, f1 = bfhi(a.x) * invl;
        float f2 = bflo(a.y) * invl, f3 = bfhi(a.y) * invl;
        uint lo = (uint)f2bf(f0) | ((uint)f2bf(f1) << 16);
        uint hi = (uint)f2bf(f2) | ((uint)f2bf(f3) << 16);
        *(uint2*)(&As[row][cu2 * 4]) = make_uint2(lo, hi);
    }
#pragma unroll
    for (int i = 0; i < 16; i++) {
        int p = t + i * 256;
        int n = p & 127, k4 = p >> 7;
        float w0 = W[(size_t)(k4 * 4 + 0) * HCH + n];
        float w1 = W[(size_t)(k4 * 4 + 1) * HCH + n];
        float w2 = W[(size_t)(k4 * 4 + 2) * HCH + n];
        float w3 = W[(size_t)(k4 * 4 + 3) * HCH + n];
        uint lo = (uint)f2bf(w0) | ((uint)f2bf(w1) << 16);
        uint hi = (uint)f2bf(w2) | ((uint)f2bf(w3) << 16);
        *(uint2*)(&Wt[n][k4 * 4]) = make_uint2(lo, hi);
    }
    __syncthreads();

    const int lane = t & 63;
    const int w = t >> 6;
    const int m_l = lane & 15;
    const int q_l = lane >> 4;

    floatx4 acc[8];
#pragma unroll
    for (int tl = 0; tl < 8; tl++) acc[tl] = (floatx4){0.f, 0.f, 0.f, 0.f};

#pragma unroll
    for (int ks = 0; ks < HCH; ks += 32) {
        short8 af = *(const short8*)(&As[w * 16 + m_l][ks + q_l * 8]);
#pragma unroll
        for (int tl = 0; tl < 8; tl++) {
            short8 bf = *(const short8*)(&Wt[tl * 16 + m_l][ks + q_l * 8]);
            acc[tl] = __builtin_amdgcn_mfma_f32_16x16x32_bf16(af, bf, acc[tl], 0, 0, 0);
        }
    }
    __syncthreads();

#pragma unroll
    for (int tl = 0; tl < 8; tl++)
#pragma unroll
        for (int r = 0; r < 4; r++)
            Cs[w * 16 + q_l * 4 + r][tl * 16 + m_l] = acc[tl][r];
    __syncthreads();

#pragma unroll
    for (int i = 0; i < 8; i++) {
        int p = t + i * 256;
        int row = p >> 5, c4 = p & 31;
        int g = mb + row;
        if (g >= M) continue;
        float4 b4 = *(const float4*)(bias + c4 * 4);
        float4 r4 = *(const float4*)(res + (size_t)g * HCH + c4 * 4);
        float4 o;
        o.x = Cs[row][c4 * 4 + 0] + b4.x + r4.x;
        o.y = Cs[row][c4 * 4 + 1] + b4.y + r4.y;
        o.z = Cs[row][c4 * 4 + 2] + b4.z + r4.z;
        o.w = Cs[row][c4 * 4 + 3] + b4.w + r4.w;
        *(float4*)(C + (size_t)g * HCH + c4 * 4) = o;
    }
}

// ================= two-pass bucketed counting sort by dst =================
constexpr int BSHIFT = 8;
constexpr int NBUCK  = ((N_NODES - 1) >> BSHIFT) + 1;   // 391
constexpr int S1_GRID = 256;
constexpr int S1_CH   = (E_EDGES + S1_GRID - 1) / S1_GRID;  // 6250
constexpr int S2_CAP  = 6144;

__global__ __launch_bounds__(256) void bucket_hist(
    const int* __restrict__ dst, int* __restrict__ bucket_total)
{
    __shared__ int cnt[NBUCK];
    const int t = threadIdx.x;
    for (int b = t; b < NBUCK; b += 256) cnt[b] = 0;
    __syncthreads();
    const int e0 = blockIdx.x * S1_CH;
    const int n = min(S1_CH, E_EDGES - e0);
    for (int i = t; i < n; i += 256)
        atomicAdd(&cnt[dst[e0 + i] >> BSHIFT], 1);
    __syncthreads();
    for (int b = t; b < NBUCK; b += 256)
        if (cnt[b]) atomicAdd(&bucket_total[b], cnt[b]);
}

__global__ __launch_bounds__(512) void bucket_scan(
    const int* __restrict__ bucket_total, int* __restrict__ bucket_start,
    int* __restrict__ bucket_cursor, int* __restrict__ offsets)
{
    __shared__ int s[512];
    const int t = threadIdx.x;
    int v = (t < NBUCK) ? bucket_total[t] : 0;
    s[t] = v;
    __syncthreads();
    for (int off = 1; off < 512; off <<= 1) {
        int a = (t >= off) ? s[t - off] : 0;
        __syncthreads();
        s[t] += a;
        __syncthreads();
    }
    int excl = s[t] - v;
    if (t < NBUCK) { bucket_start[t] = excl; bucket_cursor[t] = excl; }
    if (t == 0) { bucket_start[NBUCK] = E_EDGES; offsets[N_NODES] = E_EDGES; }
}

__global__ __launch_bounds__(256) void sort_scatter1(
    const int* __restrict__ src, const int* __restrict__ dst,
    int* __restrict__ bucket_cursor, int2* __restrict__ tmp)
{
    __shared__ int ls[S1_CH];
    __shared__ int ld[S1_CH];
    __shared__ int cnt[NBUCK];
    const int t = threadIdx.x;
    for (int b = t; b < NBUCK; b += 256) cnt[b] = 0;
    __syncthreads();
    const int e0 = blockIdx.x * S1_CH;
    const int n = min(S1_CH, E_EDGES - e0);
    for (int i = t; i < n; i += 256) {
        int d = dst[e0 + i];
        ls[i] = src[e0 + i];
        ld[i] = d;
        atomicAdd(&cnt[d >> BSHIFT], 1);
    }
    __syncthreads();
    for (int b = t; b < NBUCK; b += 256) {
        int c = cnt[b];
        cnt[b] = c ? atomicAdd(&bucket_cursor[b], c) : 0;
    }
    __syncthreads();
    for (int i = t; i < n; i += 256) {
        int d = ld[i];
        int pos = atomicAdd(&cnt[d >> BSHIFT], 1);
        tmp[pos] = make_int2(ls[i], d);
    }
}

__global__ __launch_bounds__(256) void sort_scatter2(
    const int2* __restrict__ tmp, const int* __restrict__ bucket_start,
    int* __restrict__ psrc, int* __restrict__ offsets)
{
    __shared__ int2 le[S2_CAP];
    __shared__ int cnt[256];
    __shared__ int s[256];
    __shared__ int cur[256];
    const int t = threadIdx.x;
    const int b = blockIdx.x;
    const int bstart = bucket_start[b];
    const int n = bucket_start[b + 1] - bstart;
    cnt[t] = 0;
    __syncthreads();
    for (int i = t; i < n; i += 256) {
        int2 e = tmp[bstart + i];
        if (i < S2_CAP) le[i] = e;
        atomicAdd(&cnt[e.y & 255], 1);
    }
    __syncthreads();
    int v = cnt[t];
    s[t] = v;
    __syncthreads();
    for (int off = 1; off < 256; off <<= 1) {
        int a = (t >= off) ? s[t - off] : 0;
        __syncthreads();
        s[t] += a;
        __syncthreads();
    }
    int excl = s[t] - v;
    int node = (b << BSHIFT) + t;
    if (node < N_NODES) offsets[node] = bstart + excl;
    cur[t] = excl;
    __syncthreads();
    for (int i = t; i < n; i += 256) {
        int2 e = (i < S2_CAP) ? le[i] : tmp[bstart + i];
        int pos = bstart + atomicAdd(&cur[e.y & 255], 1);
        psrc[pos] = e.x;
    }
}

// ============ FUSED segment reduce: ONE NODE PER 16-LANE GROUP ============
// Wave = 4 independent groups; group handles node d fully (4-wide clamped batches).
// Lane sub: 16B of the 256B kv row = 8 k-fp8 (.xy) + 8 v-fp8 (.zw), channels sub*8..+7.
// Pair lanes (xor 1) = two halves of head sub>>1; shfl_xor(1) completes the dot.
constexpr int FU_BLOCKS = 2048;
constexpr int FU_GROUPS = FU_BLOCKS * 16;   // 16-lane groups total

__device__ __forceinline__ float edge_w(
    uint4 e, floatx2 q0, floatx2 q1, floatx2 q2, floatx2 q3)
{
    floatx2 dp = q0 * __builtin_amdgcn_cvt_pk_f32_fp8((int)e.x, false);
    dp += q1 * __builtin_amdgcn_cvt_pk_f32_fp8((int)e.x, true);
    dp += q2 * __builtin_amdgcn_cvt_pk_f32_fp8((int)e.y, false);
    dp += q3 * __builtin_amdgcn_cvt_pk_f32_fp8((int)e.y, true);
    float p = dp.x + dp.y;
    p += __shfl_xor(p, 1);
    return __expf(p * 0.25f);
}
__device__ __forceinline__ void edge_acc(
    uint4 e, float wgt, floatx2& a01, floatx2& a23, floatx2& a45, floatx2& a67)
{
    floatx2 wv = {wgt, wgt};
    a01 += wv * __builtin_amdgcn_cvt_pk_f32_fp8((int)e.z, false);
    a23 += wv * __builtin_amdgcn_cvt_pk_f32_fp8((int)e.z, true);
    a45 += wv * __builtin_amdgcn_cvt_pk_f32_fp8((int)e.w, false);
    a67 += wv * __builtin_amdgcn_cvt_pk_f32_fp8((int)e.w, true);
}

__global__ __launch_bounds__(256) void edge_fused(
    const unsigned char* __restrict__ qe, const unsigned char* __restrict__ kv,
    const int* __restrict__ psrc, const int* __restrict__ offsets,
    ushort* __restrict__ attended, float* __restrict__ block_l)
{
    const int t = threadIdx.x;
    const int sub = t & 15;            // 16B chunk within row
    const int gg0 = blockIdx.x * 16 + (t >> 4);   // global group id

    float lsum = 0.f;

    for (int d = gg0; d < N_NODES; d += FU_GROUPS) {
        const int start = offsets[d];
        const int end   = offsets[d + 1];

        uint2 qw = *(const uint2*)(qe + (size_t)d * 128 + sub * 8);
        floatx2 q0 = __builtin_amdgcn_cvt_pk_f32_fp8((int)qw.x, false);
        floatx2 q1 = __builtin_amdgcn_cvt_pk_f32_fp8((int)qw.x, true);
        floatx2 q2 = __builtin_amdgcn_cvt_pk_f32_fp8((int)qw.y, false);
        floatx2 q3 = __builtin_amdgcn_cvt_pk_f32_fp8((int)qw.y, true);

        floatx2 a01 = {0.f, 0.f}, a23 = {0.f, 0.f}, a45 = {0.f, 0.f}, a67 = {0.f, 0.f};

        for (int i = start; i < end; i += 4) {
            // clamped 4-wide batch; invalid edges get wgt = 0
            int i1 = min(i + 1, end - 1);
            int i2 = min(i + 2, end - 1);
            int i3 = min(i + 3, end - 1);
            int s0 = psrc[i];
            int s1 = psrc[i1];
            int s2 = psrc[i2];
            int s3 = psrc[i3];
            uint4 e0 = *(const uint4*)(kv + (size_t)s0 * 256 + sub * 16);
            uint4 e1 = *(const uint4*)(kv + (size_t)s1 * 256 + sub * 16);
            uint4 e2 = *(const uint4*)(kv + (size_t)s2 * 256 + sub * 16);
            uint4 e3 = *(const uint4*)(kv + (size_t)s3 * 256 + sub * 16);

            float w0 = edge_w(e0, q0, q1, q2, q3);
            float w1 = edge_w(e1, q0, q1, q2, q3);
            float w2 = edge_w(e2, q0, q1, q2, q3);
            float w3 = edge_w(e3, q0, q1, q2, q3);
            if (i + 1 >= end) w1 = 0.f;
            if (i + 2 >= end) w2 = 0.f;
            if (i + 3 >= end) w3 = 0.f;
            lsum += w0 + w1 + w2 + w3;   // pair lanes double-count; halved in reduction

            edge_acc(e0, w0, a01, a23, a45, a67);
            edge_acc(e1, w1, a01, a23, a45, a67);
            edge_acc(e2, w2, a01, a23, a45, a67);
            edge_acc(e3, w3, a01, a23, a45, a67);
        }

        uint4 o;
        o.x = (uint)f2bf(a01.x) | ((uint)f2bf(a01.y) << 16);
        o.y = (uint)f2bf(a23.x) | ((uint)f2bf(a23.y) << 16);
        o.z = (uint)f2bf(a45.x) | ((uint)f2bf(a45.y) << 16);
        o.w = (uint)f2bf(a67.x) | ((uint)f2bf(a67.y) << 16);
        *(uint4*)(attended + (size_t)d * HCH + sub * 8) = o;
    }

    // block-level per-head L reduction; head = (t&15)>>1, pair lanes double-count -> x0.5
    __shared__ float sl[256];
    sl[t] = lsum;
    __syncthreads();
    if (t < 8) {
        float L = 0.f;
        for (int base = 0; base < 256; base += 16)
            L += sl[base + 2 * t] + sl[base + 2 * t + 1];
        block_l[blockIdx.x * 8 + t] = 0.5f * L;
    }
}

__global__ __launch_bounds__(256) void reduce_l(
    const float* __restrict__ block_l, float* __restrict__ head_invl, int nblk)
{
    const int t = threadIdx.x;
    float l = 0.f;
    for (int i = t; i < nblk * 8; i += 256) l += block_l[i];
    __shared__ float sl[256];
    sl[t] = l;
    __syncthreads();
    if (t < 8) {
        float L = 0.f;
        for (int i = t; i < 256; i += 8) L += sl[i];
        head_invl[t] = 1.0f / L;
    }
}

extern "C" void kernel_launch(void* const* d_in, const int* in_sizes, int n_in,
                              void* d_out, int out_size, void* d_ws, size_t ws_size,
                              hipStream_t stream)
{
    const float* x  = (const float*)d_in[0];
    const int* eidx = (const int*)d_in[1];
    const float* Wq = (const float*)d_in[2];
    const float* bq = (const float*)d_in[3];
    const float* Wk = (const float*)d_in[4];
    const float* bk = (const float*)d_in[5];
    const float* Wv = (const float*)d_in[6];
    const float* bv = (const float*)d_in[7];
    const float* Wo = (const float*)d_in[8];
    const float* bo = (const float*)d_in[9];
    float* out = (float*)d_out;

    char* ws = (char*)d_ws;
    constexpr size_t SZ_Q8  = (size_t)N_NODES * HCH;          // 12.8 MB fp8 q
    constexpr size_t SZ_KV8 = (size_t)N_NODES * HCH * 2;      // 25.6 MB fp8 kv interleaved
    constexpr size_t SZ_ATT = (size_t)N_NODES * HCH * 2;      // 25.6 MB bf16 attended
    constexpr size_t SZ_PS  = (size_t)E_EDGES * sizeof(int);  // 6.4 MB
    constexpr size_t SZ_TMP = (size_t)E_EDGES * sizeof(int2); // 12.8 MB
    size_t off = 0;
    unsigned char* qe  = (unsigned char*)(ws + off); off += SZ_Q8;
    unsigned char* kvb = (unsigned char*)(ws + off); off += SZ_KV8;
    ushort* attended = (ushort*)(ws + off); off += SZ_ATT;
    int*    psrc     = (int*)(ws + off);    off += SZ_PS;
    int2*   tmp      = (int2*)(ws + off);   off += SZ_TMP;
    int*    offsets  = (int*)(ws + off);    off += ((size_t)N_NODES + 1) * 4 + 8;
    int*    bucket_total  = (int*)(ws + off); off += (NBUCK + 1) * 4;
    int*    bucket_start  = (int*)(ws + off); off += (NBUCK + 1) * 4;
    int*    bucket_cursor = (int*)(ws + off); off += (NBUCK + 1) * 4;
    float*  block_l   = (float*)(ws + off); off += (size_t)FU_BLOCKS * 8 * sizeof(float);
    float*  head_invl = (float*)(ws + off); off += 32;
    const int* src = eidx;
    const int* dst = eidx + E_EDGES;

    dim3 blk(256);
    const int gblocks = (N_NODES + 63) / 64;

    gemm_qkv<<<dim3(gblocks, 3), blk, 0, stream>>>(x, Wq, Wk, Wv, bq, bk, bv, qe, kvb, N_NODES);

    hipMemsetAsync(bucket_total, 0, (NBUCK + 1) * 4, stream);
    bucket_hist<<<S1_GRID, blk, 0, stream>>>(dst, bucket_total);
    bucket_scan<<<1, 512, 0, stream>>>(bucket_total, bucket_start, bucket_cursor, offsets);
    sort_scatter1<<<S1_GRID, blk, 0, stream>>>(src, dst, bucket_cursor, tmp);
    sort_scatter2<<<NBUCK, blk, 0, stream>>>(tmp, bucket_start, psrc, offsets);

    edge_fused<<<FU_BLOCKS, blk, 0, stream>>>(qe, kvb, psrc, offsets, attended, block_l);
    reduce_l<<<1, blk, 0, stream>>>(block_l, head_invl, FU_BLOCKS);

    gemm_out<<<gblocks, blk, 0, stream>>>(attended, Wo, bo, x, head_invl, out, N_NODES);
}